// Round 10
// baseline (394.679 us; speedup 1.0000x reference)
//
#include <hip/hip_runtime.h>
#include <math.h>

#define B_N 8192
#define D_N 512
#define S_N 5
#define C_N 2048
#define H_N 4

typedef __attribute__((ext_vector_type(8))) short bf16x8;
typedef __attribute__((ext_vector_type(4))) float floatx4;

__device__ __forceinline__ float bf2f(short u) {
  union { unsigned int i; float f; } c;
  c.i = ((unsigned int)(unsigned short)u) << 16;
  return c.f;
}
__device__ __forceinline__ short f2bf(float f) {
  union { float f; unsigned int i; } c; c.f = f;
  unsigned int x = c.i;
  x += 0x7fffu + ((x >> 16) & 1u);   // round-to-nearest-even
  return (short)(x >> 16);
}
__device__ __forceinline__ unsigned long long pack4(float a, float b, float c, float d) {
  return (unsigned long long)(unsigned short)f2bf(a)
       | ((unsigned long long)(unsigned short)f2bf(b) << 16)
       | ((unsigned long long)(unsigned short)f2bf(c) << 32)
       | ((unsigned long long)(unsigned short)f2bf(d) << 48);
}

// ---------------- prep: f->bf16 cvt + WqT transpose + Wk->bf16 (R8 verbatim) ----------
__global__ __launch_bounds__(256) void k_prep(
    const float* __restrict__ f, const float* __restrict__ Wq,
    const float* __restrict__ Wk, short* __restrict__ fbf,
    short* __restrict__ WqT, short* __restrict__ Wkb) {
  __shared__ float lds[64][65];
  const int bx = blockIdx.x, t = threadIdx.x;
  if (bx < 2048) {
    int i = bx * 256 + t;
    const floatx4* p = (const floatx4*)(f + (size_t)i * 8);
    floatx4 a = p[0], b = p[1];
    *(unsigned long long*)(fbf + (size_t)i * 8)     = pack4(a[0], a[1], a[2], a[3]);
    *(unsigned long long*)(fbf + (size_t)i * 8 + 4) = pack4(b[0], b[1], b[2], b[3]);
  } else if (bx < 2112) {
    const int bb = bx - 2048;
    const int r0 = (bb >> 3) * 64, c0 = (bb & 7) * 64;
#pragma unroll
    for (int i = 0; i < 16; ++i) {
      int r = i * 4 + (t >> 6), c = t & 63;
      lds[r][c] = Wq[(size_t)(r0 + r) * 512 + c0 + c];
    }
    __syncthreads();
#pragma unroll
    for (int i = 0; i < 16; ++i) {
      int cL = i * 4 + (t >> 6), rL = t & 63;
      WqT[(size_t)(c0 + cL) * 512 + r0 + rL] = f2bf(lds[rL][cL]);
    }
  } else {
    const int base = (bx - 2112) * 8192 + t * 4;
#pragma unroll
    for (int i = 0; i < 8; ++i) {
      int idx = base + i * 1024;
      floatx4 v = *(const floatx4*)(Wk + idx);
      *(unsigned long long*)(Wkb + idx) = pack4(v[0], v[1], v[2], v[3]);
    }
  }
}

__device__ __forceinline__ void gll(const short* g, short* l) {
  __builtin_amdgcn_global_load_lds(
      (const __attribute__((address_space(1))) unsigned int*)(g),
      (__attribute__((address_space(3))) unsigned int*)(l), 16, 0, 0);
}

// ---------------- gemmQ: BM=64 tile + qt epilogue (R9 verbatim, passed) ----------------
__global__ __launch_bounds__(256) void k_gemm64(
    const short* __restrict__ A, int lda,
    const short* __restrict__ BT, int ldb,
    short* __restrict__ O, int ldo,
    const float* __restrict__ bias, int K,
    float* __restrict__ qtp, const float* __restrict__ bkp) {
  __shared__ __align__(16) short As[2][2048];
  __shared__ __align__(16) short Bs[2][4096];
  __shared__ float qtLds[64][2];

  const int tid = threadIdx.x;
  const int lane = tid & 63;
  const int wid = tid >> 6;
  const int wr = wid >> 1, wc = wid & 1;
  const int row0 = blockIdx.y * 64;
  const int col0 = blockIdx.x * 128;

  const int r1 = tid >> 2, hk = tid & 3;
  const short* Ag1 = A + (size_t)(row0 + r1) * lda + hk * 8;
  const short* Bg1 = BT + (size_t)(col0 + r1) * ldb + hk * 8;
  const short* Bg2 = BT + (size_t)(col0 + 64 + r1) * ldb + hk * 8;

  floatx4 acc[2][4];
  const floatx4 zero = {0.0f, 0.0f, 0.0f, 0.0f};
#pragma unroll
  for (int m = 0; m < 2; ++m)
#pragma unroll
    for (int n = 0; n < 4; ++n) acc[m][n] = zero;

  const int NT = K >> 5;
  int cur = 0;

  auto stage = [&](int q, int kb) {
    gll(Ag1 + kb, &As[q][tid * 8]);
    gll(Bg1 + kb, &Bs[q][tid * 8]);
    gll(Bg2 + kb, &Bs[q][tid * 8 + 2048]);
  };

  stage(0, 0);
  __syncthreads();

  for (int t = 0; t < NT; ++t) {
    if (t + 1 < NT) stage(cur ^ 1, (t + 1) * 32);
    bf16x8 af[2], bfr[4];
#pragma unroll
    for (int m = 0; m < 2; ++m)
      af[m] = *(const bf16x8*)&As[cur][(wr * 32 + m * 16 + (lane & 15)) * 32 + (lane >> 4) * 8];
#pragma unroll
    for (int n = 0; n < 4; ++n)
      bfr[n] = *(const bf16x8*)&Bs[cur][(wc * 64 + n * 16 + (lane & 15)) * 32 + (lane >> 4) * 8];
#pragma unroll
    for (int m = 0; m < 2; ++m)
#pragma unroll
      for (int n = 0; n < 4; ++n)
        acc[m][n] = __builtin_amdgcn_mfma_f32_16x16x32_bf16(af[m], bfr[n], acc[m][n], 0, 0, 0);
    __syncthreads();
    cur ^= 1;
  }

  float qp[2][4] = {{0, 0, 0, 0}, {0, 0, 0, 0}};
#pragma unroll
  for (int m = 0; m < 2; ++m) {
    int rowb = row0 + wr * 32 + m * 16 + (lane >> 4) * 4;
#pragma unroll
    for (int n = 0; n < 4; ++n) {
      int lcol = col0 + wc * 64 + n * 16 + (lane & 15);
      float bv = bias[lcol];
      float bkv = bkp[lcol];
#pragma unroll
      for (int j = 0; j < 4; ++j) {
        float q = acc[m][n][j] + bv;
        O[(size_t)(rowb + j) * ldo + lcol] = f2bf(q);
        qp[m][j] += q * bkv;
      }
    }
  }

#pragma unroll
  for (int m = 0; m < 2; ++m)
#pragma unroll
    for (int j = 0; j < 4; ++j) {
      float p = qp[m][j];
      p += __shfl_xor(p, 1, 64);
      p += __shfl_xor(p, 2, 64);
      p += __shfl_xor(p, 4, 64);
      p += __shfl_xor(p, 8, 64);
      int lrow = wr * 32 + m * 16 + (lane >> 4) * 4 + j;
      if ((lane & 15) == 0) qtLds[lrow][wc] = p;
    }
  __syncthreads();
  if (tid < 64)
    qtp[(size_t)(row0 + tid) * H_N + blockIdx.x] = qtLds[tid][0] + qtLds[tid][1];
}

// ---------------- gemmRS: K=512 gemm64 loop; consume R in-register every 4 K-steps -----
// grid (4 a-chunks, 128 row-tiles). Head z = t>>2. No R output; atomic partials:
// scoresP[b][h][s], ssP[b][s], fsP[b][s], ffP[b]  (pre-zeroed).
__global__ __launch_bounds__(256) void k_gemmRS(
    const short* __restrict__ A,            // Qbf [8192][512]
    const short* __restrict__ BT,           // Wkb [512][512]
    const float* __restrict__ sf, const float* __restrict__ f,
    const float* __restrict__ emb,
    float* __restrict__ scoresP, float* __restrict__ ssP,
    float* __restrict__ fsP, float* __restrict__ ffP) {
  __shared__ __align__(16) short As[2][2048];
  __shared__ __align__(16) short Bs[2][4096];

  const int tid = threadIdx.x;
  const int lane = tid & 63;
  const int wid = tid >> 6;
  const int wr = wid >> 1, wc = wid & 1;
  const int row0 = blockIdx.y * 64;
  const int col0 = blockIdx.x * 128;

  const int r1 = tid >> 2, hk = tid & 3;
  const short* Ag1 = A + (size_t)(row0 + r1) * 512 + hk * 8;
  const short* Bg1 = BT + (size_t)(col0 + r1) * 512 + hk * 8;
  const short* Bg2 = BT + (size_t)(col0 + 64 + r1) * 512 + hk * 8;

  // per-lane geometry for consume
  const int rbase = row0 + wr * 32 + (lane >> 4) * 4;   // + m*16 + j
  const int acolL = col0 + wc * 64 + (lane & 15);       // + n*16

  floatx4 acc[2][4];
  const floatx4 zero = {0.0f, 0.0f, 0.0f, 0.0f};
#pragma unroll
  for (int m = 0; m < 2; ++m)
#pragma unroll
    for (int n = 0; n < 4; ++n) acc[m][n] = zero;

  int cur = 0;
  auto stage = [&](int q, int kb) {
    gll(Ag1 + kb, &As[q][tid * 8]);
    gll(Bg1 + kb, &Bs[q][tid * 8]);
    gll(Bg2 + kb, &Bs[q][tid * 8 + 2048]);
  };

  stage(0, 0);
  __syncthreads();

  for (int t = 0; t < 16; ++t) {          // 16 K-steps = 4 heads x 4
    if (t + 1 < 16) stage(cur ^ 1, (t + 1) * 32);
    bf16x8 af[2], bfr[4];
#pragma unroll
    for (int m = 0; m < 2; ++m)
      af[m] = *(const bf16x8*)&As[cur][(wr * 32 + m * 16 + (lane & 15)) * 32 + (lane >> 4) * 8];
#pragma unroll
    for (int n = 0; n < 4; ++n)
      bfr[n] = *(const bf16x8*)&Bs[cur][(wc * 64 + n * 16 + (lane & 15)) * 32 + (lane >> 4) * 8];
#pragma unroll
    for (int m = 0; m < 2; ++m)
#pragma unroll
      for (int n = 0; n < 4; ++n)
        acc[m][n] = __builtin_amdgcn_mfma_f32_16x16x32_bf16(af[m], bfr[n], acc[m][n], 0, 0, 0);

    if ((t & 3) == 3) {
      const int z = t >> 2;               // head just completed
      // ---- consume acc (R tile for head z) with sfe; barrier-free, direct global ----
#pragma unroll
      for (int s = 0; s < S_N; ++s) {
        float ps[2][4] = {{0, 0, 0, 0}, {0, 0, 0, 0}};
        float pss[2][4] = {{0, 0, 0, 0}, {0, 0, 0, 0}};
        float pfs[2][4] = {{0, 0, 0, 0}, {0, 0, 0, 0}};
        float pff[2][4] = {{0, 0, 0, 0}, {0, 0, 0, 0}};
#pragma unroll
        for (int n = 0; n < 4; ++n) {
          float evn = emb[s * 512 + acolL + n * 16];
#pragma unroll
          for (int m = 0; m < 2; ++m)
#pragma unroll
            for (int j = 0; j < 4; ++j) {
              int brow = rbase + m * 16 + j;
              float sv = sf[((size_t)s * B_N + brow) * 512 + acolL + n * 16];
              ps[m][j] += acc[m][n][j] * (sv + evn);
              if (z == 0) {
                float fvv = f[(size_t)brow * 512 + acolL + n * 16];
                pss[m][j] += sv * sv;
                pfs[m][j] += fvv * sv;
                if (s == 0) pff[m][j] += fvv * fvv;
              }
            }
        }
#pragma unroll
        for (int m = 0; m < 2; ++m)
#pragma unroll
          for (int j = 0; j < 4; ++j) {
            float p = ps[m][j];
            p += __shfl_xor(p, 1, 64);
            p += __shfl_xor(p, 2, 64);
            p += __shfl_xor(p, 4, 64);
            p += __shfl_xor(p, 8, 64);
            int brow = rbase + m * 16 + j;
            if ((lane & 15) == 0)
              atomicAdd(&scoresP[(size_t)brow * 20 + z * 5 + s], p);
            if (z == 0) {
              float u = pss[m][j], v = pfs[m][j];
              u += __shfl_xor(u, 1, 64); v += __shfl_xor(v, 1, 64);
              u += __shfl_xor(u, 2, 64); v += __shfl_xor(v, 2, 64);
              u += __shfl_xor(u, 4, 64); v += __shfl_xor(v, 4, 64);
              u += __shfl_xor(u, 8, 64); v += __shfl_xor(v, 8, 64);
              if ((lane & 15) == 0) {
                atomicAdd(&ssP[(size_t)brow * 5 + s], u);
                atomicAdd(&fsP[(size_t)brow * 5 + s], v);
              }
              if (s == 0) {
                float w = pff[m][j];
                w += __shfl_xor(w, 1, 64);
                w += __shfl_xor(w, 2, 64);
                w += __shfl_xor(w, 4, 64);
                w += __shfl_xor(w, 8, 64);
                if ((lane & 15) == 0) atomicAdd(&ffP[brow], w);
              }
            }
          }
      }
      // re-zero acc for next head
#pragma unroll
      for (int m = 0; m < 2; ++m)
#pragma unroll
        for (int n = 0; n < 4; ++n) acc[m][n] = zero;
    }
    __syncthreads();
    cur ^= 1;
  }
}

// ---------------- fused2: finalize (from partials) + logits mix. 1 wave per row. -------
__global__ __launch_bounds__(256) void k_fused2(
    const float* __restrict__ qt, const float* __restrict__ scoresP,
    const float* __restrict__ ssP, const float* __restrict__ fsP,
    const float* __restrict__ ffP, const float* __restrict__ temp,
    const float* __restrict__ attn_w, const float* __restrict__ logits,
    float* __restrict__ out, float* __restrict__ comb_out) {
  const int lane = threadIdx.x & 63;
  const int wid = threadIdx.x >> 6;
  const int b = blockIdx.x * 4 + wid;

  const floatx4 qtv = *(const floatx4*)(qt + (size_t)b * H_N);
  const float* scp = scoresP + (size_t)b * 20;
  const float* ssp = ssP + (size_t)b * 5;
  const float* fsp = fsP + (size_t)b * 5;
  const float ffv = ffP[b];
  const float t = fabsf(temp[0]);

  float amha[S_N] = {0, 0, 0, 0, 0};
  const float inv_mha = 1.0f / (sqrtf(128.0f) * t);
#pragma unroll
  for (int h = 0; h < H_N; ++h) {
    float lg[S_N];
#pragma unroll
    for (int s = 0; s < S_N; ++s) lg[s] = (scp[h * 5 + s] + qtv[h]) * inv_mha;
    float mx = lg[0];
#pragma unroll
    for (int s = 1; s < S_N; ++s) mx = fmaxf(mx, lg[s]);
    float e[S_N], sum = 0;
#pragma unroll
    for (int s = 0; s < S_N; ++s) { e[s] = __expf(lg[s] - mx); sum += e[s]; }
    float isum = 0.25f / sum;
#pragma unroll
    for (int s = 0; s < S_N; ++s) amha[s] += e[s] * isum;
  }

  float ageo[S_N];
  {
    const float nf = fmaxf(sqrtf(ffv), 1e-12f);
    float g[S_N];
#pragma unroll
    for (int s = 0; s < S_N; ++s) {
      float ns = fmaxf(sqrtf(ssp[s]), 1e-12f);
      float cs0 = fsp[s] / (nf * ns);
      cs0 = fminf(fmaxf(cs0, -1.0f + 1e-7f), 1.0f - 1e-7f);
      g[s] = __expf(-acosf(cs0) / t);
    }
    float mx = g[0];
#pragma unroll
    for (int s = 1; s < S_N; ++s) mx = fmaxf(mx, g[s]);
    float sum = 0;
#pragma unroll
    for (int s = 0; s < S_N; ++s) { ageo[s] = __expf(g[s] - mx); sum += ageo[s]; }
#pragma unroll
    for (int s = 0; s < S_N; ++s) ageo[s] /= sum;
  }

  float acay[S_N];
  {
    const float SQ2 = 1.41421356237309515f;
    const float Aff = 0.72f;
    const float Ass = 0.72f - 0.32f * SQ2;
    const float Afs = -(8.0f + 4.0f * SQ2) / 25.0f;
    float lg[S_N];
#pragma unroll
    for (int s = 0; s < S_N; ++s)
      lg[s] = (Aff * ffv + Ass * ssp[s] + Afs * fsp[s]) / t;
    float mx = lg[0];
#pragma unroll
    for (int s = 1; s < S_N; ++s) mx = fmaxf(mx, lg[s]);
    float sum = 0;
#pragma unroll
    for (int s = 0; s < S_N; ++s) { acay[s] = __expf(lg[s] - mx); sum += acay[s]; }
#pragma unroll
    for (int s = 0; s < S_N; ++s) acay[s] /= sum;
  }

  float w0 = attn_w[0], w1 = attn_w[1], w2 = attn_w[2];
  float wm = fmaxf(w0, fmaxf(w1, w2));
  float e0 = __expf(w0 - wm), e1 = __expf(w1 - wm), e2 = __expf(w2 - wm);
  float wsum = e0 + e1 + e2;
  w0 = e0 / wsum; w1 = e1 / wsum; w2 = e2 / wsum;

  float cb[S_N], csum = 0;
#pragma unroll
  for (int s = 0; s < S_N; ++s) {
    cb[s] = w0 * amha[s] + w1 * ageo[s] + w2 * acay[s];
    csum += cb[s];
  }
  float ic = 1.0f / csum;
  float cbn[S_N];
#pragma unroll
  for (int s = 0; s < S_N; ++s) cbn[s] = cb[s] * ic;
  if (lane == 0) {
#pragma unroll
    for (int s = 0; s < S_N; ++s) comb_out[(size_t)b * S_N + s] = cbn[s];
  }

  const floatx4 fz = {0.f, 0.f, 0.f, 0.f};
#pragma unroll
  for (int cj = 0; cj < 4; ++cj) {
    const int c0 = cj * 512 + lane * 8;
    floatx4 accA = fz, accB = fz;
#pragma unroll
    for (int s = 0; s < S_N; ++s) {
      const float* lp = logits + ((size_t)s * B_N + b) * C_N + c0;
      floatx4 lA = *(const floatx4*)lp;
      floatx4 lB = *(const floatx4*)(lp + 4);
      accA += lA * cbn[s];
      accB += lB * cbn[s];
    }
    float* op = out + (size_t)b * C_N + c0;
    *(floatx4*)op = accA;
    *(floatx4*)(op + 4) = accB;
  }
}

extern "C" void kernel_launch(void* const* d_in, const int* in_sizes, int n_in,
                              void* d_out, int out_size, void* d_ws, size_t ws_size,
                              hipStream_t stream) {
  const float* features = (const float*)d_in[0];
  const float* logits   = (const float*)d_in[1];
  const float* sf       = (const float*)d_in[2];
  const float* Wq       = (const float*)d_in[3];
  const float* bq       = (const float*)d_in[4];
  const float* Wk       = (const float*)d_in[5];
  const float* bk       = (const float*)d_in[6];
  const float* emb      = (const float*)d_in[9];
  const float* temp     = (const float*)d_in[10];
  const float* attn_w   = (const float*)d_in[11];

  float* out  = (float*)d_out;
  float* comb = out + (size_t)B_N * C_N;

  char* w = (char*)d_ws;
  short* fbf     = (short*)(w);                 // 8192*512 bf16 = 8.39 MB
  short* Qbf     = (short*)(w + 8388608);       // 8192*512 bf16 = 8.39 MB
  short* WqT     = (short*)(w + 16777216);      // 512*512  bf16 = 0.52 MB
  short* Wkb     = (short*)(w + 17301504);      // 512*512  bf16 = 0.52 MB
  float* qtb     = (float*)(w + 17825792);      // 8192*4   f32
  float* scoresP = (float*)(w + 17956864);      // 8192*20  f32 = 655360 B
  float* ssP     = (float*)(w + 18612224);      // 8192*5   f32 = 163840 B
  float* fsP     = (float*)(w + 18776064);      // 8192*5   f32 = 163840 B
  float* ffP     = (float*)(w + 18939904);      // 8192     f32 = 32768 B

  // 0. zero partial accumulators (scoresP..ffP contiguous: 1,015,808 B)
  hipMemsetAsync(scoresP, 0, 1015808, stream);
  // 1. f->bf16 + WqT transpose + Wk->bf16
  k_prep<<<dim3(2144), dim3(256), 0, stream>>>(features, Wq, Wk, fbf, WqT, Wkb);
  // 2. Q = f @ Wq + bq  (+ qt[b][h] = Q_h . bk_h; block.x == head)
  k_gemm64<<<dim3(4, 128), dim3(256), 0, stream>>>(fbf, 512, WqT, 512, Qbf, 512,
                                                   bq, 512, qtb, bk);
  // 3. R in registers + consume with sfe -> scores/ss/fs/ff partials (no Rbf)
  k_gemmRS<<<dim3(4, 128), dim3(256), 0, stream>>>(Qbf, Wkb, sf, features, emb,
                                                   scoresP, ssP, fsP, ffP);
  // 4. finalize three attentions + fuse + logits mix
  k_fused2<<<dim3(2048), dim3(256), 0, stream>>>(qtb, scoresP, ssP, fsP, ffP,
                                                 temp, attn_w, logits, out, comb);
}

// Round 11
// 188.448 us; speedup vs baseline: 2.0944x; 2.0944x over previous
//
#include <hip/hip_runtime.h>
#include <math.h>

#define B_N 8192
#define D_N 512
#define S_N 5
#define C_N 2048
#define H_N 4

typedef __attribute__((ext_vector_type(8))) short bf16x8;
typedef __attribute__((ext_vector_type(4))) float floatx4;

__device__ __forceinline__ float bf2f(short u) {
  union { unsigned int i; float f; } c;
  c.i = ((unsigned int)(unsigned short)u) << 16;
  return c.f;
}
__device__ __forceinline__ short f2bf(float f) {
  union { float f; unsigned int i; } c; c.f = f;
  unsigned int x = c.i;
  x += 0x7fffu + ((x >> 16) & 1u);   // round-to-nearest-even
  return (short)(x >> 16);
}
__device__ __forceinline__ unsigned long long pack4(float a, float b, float c, float d) {
  return (unsigned long long)(unsigned short)f2bf(a)
       | ((unsigned long long)(unsigned short)f2bf(b) << 16)
       | ((unsigned long long)(unsigned short)f2bf(c) << 32)
       | ((unsigned long long)(unsigned short)f2bf(d) << 48);
}

// ---------------- pre2: wave-per-row stats (exact f32 ss/fs/ff) + fbf + sfeb,
//                  plus WqT / WkT transposes in tail blocks ----------------
// blocks 0..2047: wave w -> row b = bx*4+w (k_stats pattern, R1-verified)
// blocks 2048..2111: WqT; 2112..2175: WkT (LDS transpose, R2-verified)
__global__ __launch_bounds__(256) void k_pre2(
    const float* __restrict__ f, const float* __restrict__ sf,
    const float* __restrict__ emb, const float* __restrict__ Wq,
    const float* __restrict__ Wk, short* __restrict__ fbf,
    short* __restrict__ sfeb, short* __restrict__ WqT, short* __restrict__ WkT,
    float* __restrict__ ssP, float* __restrict__ fsP, float* __restrict__ ffP) {
  __shared__ float lds[64][65];
  const int bx = blockIdx.x, t = threadIdx.x;
  if (bx < 2048) {
    const int lane = t & 63;
    const int wid = t >> 6;
    const int b = bx * 4 + wid;
    const int a0 = lane * 8;

    const floatx4* fp = (const floatx4*)(f + (size_t)b * D_N + a0);
    floatx4 fA = fp[0], fB = fp[1];
    float fv[8];
#pragma unroll
    for (int j = 0; j < 4; ++j) { fv[j] = fA[j]; fv[4 + j] = fB[j]; }
    float ffp = 0;
#pragma unroll
    for (int j = 0; j < 8; ++j) ffp += fv[j] * fv[j];
    *(unsigned long long*)(fbf + (size_t)b * D_N + a0)     = pack4(fv[0], fv[1], fv[2], fv[3]);
    *(unsigned long long*)(fbf + (size_t)b * D_N + a0 + 4) = pack4(fv[4], fv[5], fv[6], fv[7]);

    float ss_[S_N], fs_[S_N];
#pragma unroll
    for (int s = 0; s < S_N; ++s) {
      const floatx4* sp = (const floatx4*)(sf + ((size_t)s * B_N + b) * D_N + a0);
      floatx4 sA = sp[0], sB = sp[1];
      const floatx4* ep = (const floatx4*)(emb + (size_t)s * D_N + a0);
      floatx4 eA = ep[0], eB = ep[1];
      float sv[8], se[8];
#pragma unroll
      for (int j = 0; j < 4; ++j) {
        sv[j] = sA[j]; sv[4 + j] = sB[j];
        se[j] = sA[j] + eA[j]; se[4 + j] = sB[j] + eB[j];
      }
      float ssp = 0, fsp = 0;
#pragma unroll
      for (int j = 0; j < 8; ++j) { ssp += sv[j] * sv[j]; fsp += fv[j] * sv[j]; }
      ss_[s] = ssp; fs_[s] = fsp;
      size_t ro = ((size_t)s * B_N + b) * D_N + a0;
      *(unsigned long long*)(sfeb + ro)     = pack4(se[0], se[1], se[2], se[3]);
      *(unsigned long long*)(sfeb + ro + 4) = pack4(se[4], se[5], se[6], se[7]);
    }

#pragma unroll
    for (int o = 1; o < 64; o <<= 1) {
      ffp += __shfl_xor(ffp, o, 64);
#pragma unroll
      for (int s = 0; s < S_N; ++s) {
        ss_[s] += __shfl_xor(ss_[s], o, 64);
        fs_[s] += __shfl_xor(fs_[s], o, 64);
      }
    }
    if (lane == 0) {
      ffP[b] = ffp;
#pragma unroll
      for (int s = 0; s < S_N; ++s) {
        ssP[(size_t)b * S_N + s] = ss_[s];
        fsP[(size_t)b * S_N + s] = fs_[s];
      }
    }
  } else {
    const bool isQ = bx < 2112;
    const int bb = isQ ? (bx - 2048) : (bx - 2112);
    const float* src = isQ ? Wq : Wk;
    short* dst = isQ ? WqT : WkT;
    const int r0 = (bb >> 3) * 64, c0 = (bb & 7) * 64;
#pragma unroll
    for (int i = 0; i < 16; ++i) {
      int r = i * 4 + (t >> 6), c = t & 63;
      lds[r][c] = src[(size_t)(r0 + r) * 512 + c0 + c];
    }
    __syncthreads();
#pragma unroll
    for (int i = 0; i < 16; ++i) {
      int cL = i * 4 + (t >> 6), rL = t & 63;
      dst[(size_t)(c0 + cL) * 512 + r0 + rL] = f2bf(lds[rL][cL]);
    }
  }
}

__device__ __forceinline__ void gll(const short* g, short* l) {
  __builtin_amdgcn_global_load_lds(
      (const __attribute__((address_space(1))) unsigned int*)(g),
      (__attribute__((address_space(3))) unsigned int*)(l), 16, 0, 0);
}

// ---------------- gemmQ: BM=64 tile + qt epilogue (R9 verbatim, passed) ----------------
__global__ __launch_bounds__(256) void k_gemm64(
    const short* __restrict__ A, int lda,
    const short* __restrict__ BT, int ldb,
    short* __restrict__ O, int ldo,
    const float* __restrict__ bias, int K,
    float* __restrict__ qtp, const float* __restrict__ bkp) {
  __shared__ __align__(16) short As[2][2048];
  __shared__ __align__(16) short Bs[2][4096];
  __shared__ float qtLds[64][2];

  const int tid = threadIdx.x;
  const int lane = tid & 63;
  const int wid = tid >> 6;
  const int wr = wid >> 1, wc = wid & 1;
  const int row0 = blockIdx.y * 64;
  const int col0 = blockIdx.x * 128;

  const int r1 = tid >> 2, hk = tid & 3;
  const short* Ag1 = A + (size_t)(row0 + r1) * lda + hk * 8;
  const short* Bg1 = BT + (size_t)(col0 + r1) * ldb + hk * 8;
  const short* Bg2 = BT + (size_t)(col0 + 64 + r1) * ldb + hk * 8;

  floatx4 acc[2][4];
  const floatx4 zero = {0.0f, 0.0f, 0.0f, 0.0f};
#pragma unroll
  for (int m = 0; m < 2; ++m)
#pragma unroll
    for (int n = 0; n < 4; ++n) acc[m][n] = zero;

  const int NT = K >> 5;
  int cur = 0;

  auto stage = [&](int q, int kb) {
    gll(Ag1 + kb, &As[q][tid * 8]);
    gll(Bg1 + kb, &Bs[q][tid * 8]);
    gll(Bg2 + kb, &Bs[q][tid * 8 + 2048]);
  };

  stage(0, 0);
  __syncthreads();

  for (int t = 0; t < NT; ++t) {
    if (t + 1 < NT) stage(cur ^ 1, (t + 1) * 32);
    bf16x8 af[2], bfr[4];
#pragma unroll
    for (int m = 0; m < 2; ++m)
      af[m] = *(const bf16x8*)&As[cur][(wr * 32 + m * 16 + (lane & 15)) * 32 + (lane >> 4) * 8];
#pragma unroll
    for (int n = 0; n < 4; ++n)
      bfr[n] = *(const bf16x8*)&Bs[cur][(wc * 64 + n * 16 + (lane & 15)) * 32 + (lane >> 4) * 8];
#pragma unroll
    for (int m = 0; m < 2; ++m)
#pragma unroll
      for (int n = 0; n < 4; ++n)
        acc[m][n] = __builtin_amdgcn_mfma_f32_16x16x32_bf16(af[m], bfr[n], acc[m][n], 0, 0, 0);
    __syncthreads();
    cur ^= 1;
  }

  float qp[2][4] = {{0, 0, 0, 0}, {0, 0, 0, 0}};
#pragma unroll
  for (int m = 0; m < 2; ++m) {
    int rowb = row0 + wr * 32 + m * 16 + (lane >> 4) * 4;
#pragma unroll
    for (int n = 0; n < 4; ++n) {
      int lcol = col0 + wc * 64 + n * 16 + (lane & 15);
      float bv = bias[lcol];
      float bkv = bkp[lcol];
#pragma unroll
      for (int j = 0; j < 4; ++j) {
        float q = acc[m][n][j] + bv;
        O[(size_t)(rowb + j) * ldo + lcol] = f2bf(q);
        qp[m][j] += q * bkv;
      }
    }
  }

#pragma unroll
  for (int m = 0; m < 2; ++m)
#pragma unroll
    for (int j = 0; j < 4; ++j) {
      float p = qp[m][j];
      p += __shfl_xor(p, 1, 64);
      p += __shfl_xor(p, 2, 64);
      p += __shfl_xor(p, 4, 64);
      p += __shfl_xor(p, 8, 64);
      int lrow = wr * 32 + m * 16 + (lane >> 4) * 4 + j;
      if ((lane & 15) == 0) qtLds[lrow][wc] = p;
    }
  __syncthreads();
  if (tid < 64)
    qtp[(size_t)(row0 + tid) * H_N + blockIdx.x] = qtLds[tid][0] + qtLds[tid][1];
}

// ---------------- gemmKS: K = sfeb @ WkT (k_gemm64 loop verbatim); epilogue dots the
// K-tile with Q (col chunk == head, so the j-sum is block-complete) -> scoresB.
// grid (4 heads, 640 row-tiles of the 40960 (s,b) rows). No K materialization.
__global__ __launch_bounds__(256) void k_gemmKS(
    const short* __restrict__ A,            // sfeb [40960][512]
    const short* __restrict__ BT,           // WkT  [512][512]
    const short* __restrict__ Qbf,          // [8192][512]
    float* __restrict__ scoresB) {          // [b][h*5+s]
  __shared__ __align__(16) short As[2][2048];
  __shared__ __align__(16) short Bs[2][4096];
  __shared__ float qtLds[64][2];

  const int tid = threadIdx.x;
  const int lane = tid & 63;
  const int wid = tid >> 6;
  const int wr = wid >> 1, wc = wid & 1;
  const int row0 = blockIdx.y * 64;       // flat (s,b) row
  const int col0 = blockIdx.x * 128;      // head chunk
  const int s = row0 >> 13;               // row0 / 8192
  const int b0 = row0 & 8191;

  const int r1 = tid >> 2, hk = tid & 3;
  const short* Ag1 = A + (size_t)(row0 + r1) * 512 + hk * 8;
  const short* Bg1 = BT + (size_t)(col0 + r1) * 512 + hk * 8;
  const short* Bg2 = BT + (size_t)(col0 + 64 + r1) * 512 + hk * 8;

  floatx4 acc[2][4];
  const floatx4 zero = {0.0f, 0.0f, 0.0f, 0.0f};
#pragma unroll
  for (int m = 0; m < 2; ++m)
#pragma unroll
    for (int n = 0; n < 4; ++n) acc[m][n] = zero;

  int cur = 0;
  auto stage = [&](int q, int kb) {
    gll(Ag1 + kb, &As[q][tid * 8]);
    gll(Bg1 + kb, &Bs[q][tid * 8]);
    gll(Bg2 + kb, &Bs[q][tid * 8 + 2048]);
  };

  stage(0, 0);
  __syncthreads();

  for (int t = 0; t < 16; ++t) {
    if (t + 1 < 16) stage(cur ^ 1, (t + 1) * 32);
    bf16x8 af[2], bfr[4];
#pragma unroll
    for (int m = 0; m < 2; ++m)
      af[m] = *(const bf16x8*)&As[cur][(wr * 32 + m * 16 + (lane & 15)) * 32 + (lane >> 4) * 8];
#pragma unroll
    for (int n = 0; n < 4; ++n)
      bfr[n] = *(const bf16x8*)&Bs[cur][(wc * 64 + n * 16 + (lane & 15)) * 32 + (lane >> 4) * 8];
#pragma unroll
    for (int m = 0; m < 2; ++m)
#pragma unroll
      for (int n = 0; n < 4; ++n)
        acc[m][n] = __builtin_amdgcn_mfma_f32_16x16x32_bf16(af[m], bfr[n], acc[m][n], 0, 0, 0);
    __syncthreads();
    cur ^= 1;
  }

  // epilogue: score partial = sum_n acc[m][n][j] * Q[b][col]; Qbf is L2-resident
  float qp[2][4] = {{0, 0, 0, 0}, {0, 0, 0, 0}};
#pragma unroll
  for (int m = 0; m < 2; ++m) {
    int rowb = b0 + wr * 32 + m * 16 + (lane >> 4) * 4;
#pragma unroll
    for (int n = 0; n < 4; ++n) {
      int lcol = col0 + wc * 64 + n * 16 + (lane & 15);
#pragma unroll
      for (int j = 0; j < 4; ++j)
        qp[m][j] += acc[m][n][j] * bf2f(Qbf[(size_t)(rowb + j) * 512 + lcol]);
    }
  }

#pragma unroll
  for (int m = 0; m < 2; ++m)
#pragma unroll
    for (int j = 0; j < 4; ++j) {
      float p = qp[m][j];
      p += __shfl_xor(p, 1, 64);
      p += __shfl_xor(p, 2, 64);
      p += __shfl_xor(p, 4, 64);
      p += __shfl_xor(p, 8, 64);
      int lrow = wr * 32 + m * 16 + (lane >> 4) * 4 + j;
      if ((lane & 15) == 0) qtLds[lrow][wc] = p;
    }
  __syncthreads();
  if (tid < 64)
    scoresB[(size_t)(b0 + tid) * 20 + blockIdx.x * 5 + s] = qtLds[tid][0] + qtLds[tid][1];
}

// ---------------- fused3: finalize + logits mix (R10 k_fused2 verbatim, passed) --------
__global__ __launch_bounds__(256) void k_fused2(
    const float* __restrict__ qt, const float* __restrict__ scoresP,
    const float* __restrict__ ssP, const float* __restrict__ fsP,
    const float* __restrict__ ffP, const float* __restrict__ temp,
    const float* __restrict__ attn_w, const float* __restrict__ logits,
    float* __restrict__ out, float* __restrict__ comb_out) {
  const int lane = threadIdx.x & 63;
  const int wid = threadIdx.x >> 6;
  const int b = blockIdx.x * 4 + wid;

  const floatx4 qtv = *(const floatx4*)(qt + (size_t)b * H_N);
  const float* scp = scoresP + (size_t)b * 20;
  const float* ssp = ssP + (size_t)b * 5;
  const float* fsp = fsP + (size_t)b * 5;
  const float ffv = ffP[b];
  const float t = fabsf(temp[0]);

  float amha[S_N] = {0, 0, 0, 0, 0};
  const float inv_mha = 1.0f / (sqrtf(128.0f) * t);
#pragma unroll
  for (int h = 0; h < H_N; ++h) {
    float lg[S_N];
#pragma unroll
    for (int s = 0; s < S_N; ++s) lg[s] = (scp[h * 5 + s] + qtv[h]) * inv_mha;
    float mx = lg[0];
#pragma unroll
    for (int s = 1; s < S_N; ++s) mx = fmaxf(mx, lg[s]);
    float e[S_N], sum = 0;
#pragma unroll
    for (int s = 0; s < S_N; ++s) { e[s] = __expf(lg[s] - mx); sum += e[s]; }
    float isum = 0.25f / sum;
#pragma unroll
    for (int s = 0; s < S_N; ++s) amha[s] += e[s] * isum;
  }

  float ageo[S_N];
  {
    const float nf = fmaxf(sqrtf(ffv), 1e-12f);
    float g[S_N];
#pragma unroll
    for (int s = 0; s < S_N; ++s) {
      float ns = fmaxf(sqrtf(ssp[s]), 1e-12f);
      float cs0 = fsp[s] / (nf * ns);
      cs0 = fminf(fmaxf(cs0, -1.0f + 1e-7f), 1.0f - 1e-7f);
      g[s] = __expf(-acosf(cs0) / t);
    }
    float mx = g[0];
#pragma unroll
    for (int s = 1; s < S_N; ++s) mx = fmaxf(mx, g[s]);
    float sum = 0;
#pragma unroll
    for (int s = 0; s < S_N; ++s) { ageo[s] = __expf(g[s] - mx); sum += ageo[s]; }
#pragma unroll
    for (int s = 0; s < S_N; ++s) ageo[s] /= sum;
  }

  float acay[S_N];
  {
    const float SQ2 = 1.41421356237309515f;
    const float Aff = 0.72f;
    const float Ass = 0.72f - 0.32f * SQ2;
    const float Afs = -(8.0f + 4.0f * SQ2) / 25.0f;
    float lg[S_N];
#pragma unroll
    for (int s = 0; s < S_N; ++s)
      lg[s] = (Aff * ffv + Ass * ssp[s] + Afs * fsp[s]) / t;
    float mx = lg[0];
#pragma unroll
    for (int s = 1; s < S_N; ++s) mx = fmaxf(mx, lg[s]);
    float sum = 0;
#pragma unroll
    for (int s = 0; s < S_N; ++s) { acay[s] = __expf(lg[s] - mx); sum += acay[s]; }
#pragma unroll
    for (int s = 0; s < S_N; ++s) acay[s] /= sum;
  }

  float w0 = attn_w[0], w1 = attn_w[1], w2 = attn_w[2];
  float wm = fmaxf(w0, fmaxf(w1, w2));
  float e0 = __expf(w0 - wm), e1 = __expf(w1 - wm), e2 = __expf(w2 - wm);
  float wsum = e0 + e1 + e2;
  w0 = e0 / wsum; w1 = e1 / wsum; w2 = e2 / wsum;

  float cb[S_N], csum = 0;
#pragma unroll
  for (int s = 0; s < S_N; ++s) {
    cb[s] = w0 * amha[s] + w1 * ageo[s] + w2 * acay[s];
    csum += cb[s];
  }
  float ic = 1.0f / csum;
  float cbn[S_N];
#pragma unroll
  for (int s = 0; s < S_N; ++s) cbn[s] = cb[s] * ic;
  if (lane == 0) {
#pragma unroll
    for (int s = 0; s < S_N; ++s) comb_out[(size_t)b * S_N + s] = cbn[s];
  }

  const floatx4 fz = {0.f, 0.f, 0.f, 0.f};
#pragma unroll
  for (int cj = 0; cj < 4; ++cj) {
    const int c0 = cj * 512 + lane * 8;
    floatx4 accA = fz, accB = fz;
#pragma unroll
    for (int s = 0; s < S_N; ++s) {
      const float* lp = logits + ((size_t)s * B_N + b) * C_N + c0;
      floatx4 lA = *(const floatx4*)lp;
      floatx4 lB = *(const floatx4*)(lp + 4);
      accA += lA * cbn[s];
      accB += lB * cbn[s];
    }
    float* op = out + (size_t)b * C_N + c0;
    *(floatx4*)op = accA;
    *(floatx4*)(op + 4) = accB;
  }
}

extern "C" void kernel_launch(void* const* d_in, const int* in_sizes, int n_in,
                              void* d_out, int out_size, void* d_ws, size_t ws_size,
                              hipStream_t stream) {
  const float* features = (const float*)d_in[0];
  const float* logits   = (const float*)d_in[1];
  const float* sf       = (const float*)d_in[2];
  const float* Wq       = (const float*)d_in[3];
  const float* bq       = (const float*)d_in[4];
  const float* Wk       = (const float*)d_in[5];
  const float* bk       = (const float*)d_in[6];
  const float* emb      = (const float*)d_in[9];
  const float* temp     = (const float*)d_in[10];
  const float* attn_w   = (const float*)d_in[11];

  float* out  = (float*)d_out;
  float* comb = out + (size_t)B_N * C_N;

  char* w = (char*)d_ws;
  short* fbf     = (short*)(w);                 // 8192*512  bf16 =  8.39 MB
  short* Qbf     = (short*)(w + 8388608);       // 8192*512  bf16 =  8.39 MB
  short* sfeb    = (short*)(w + 16777216);      // 40960*512 bf16 = 41.94 MB
  short* WqT     = (short*)(w + 58720256);      // 512*512   bf16
  short* WkT     = (short*)(w + 59244544);      // 512*512   bf16
  float* qtb     = (float*)(w + 59768832);      // 8192*4    f32
  float* scoresB = (float*)(w + 59899904);      // 8192*20   f32
  float* ssP     = (float*)(w + 60555264);      // 8192*5    f32
  float* fsP     = (float*)(w + 60719104);      // 8192*5    f32
  float* ffP     = (float*)(w + 60882944);      // 8192      f32

  // 1. stats (exact f32) + fbf + sfeb + weight transposes
  k_pre2<<<dim3(2176), dim3(256), 0, stream>>>(features, sf, emb, Wq, Wk,
                                               fbf, sfeb, WqT, WkT, ssP, fsP, ffP);
  // 2. Q = f @ Wq + bq  (+ qt[b][h] = Q_h . bk_h; block.x == head)
  k_gemm64<<<dim3(4, 128), dim3(256), 0, stream>>>(fbf, 512, WqT, 512, Qbf, 512,
                                                   bq, 512, qtb, bk);
  // 3. K-GEMM with fused score epilogue: scoresB[b][h*5+s] = sfe(s,b) . R(b,h)
  k_gemmKS<<<dim3(4, 640), dim3(256), 0, stream>>>(sfeb, WkT, Qbf, scoresB);
  // 4. finalize three attentions + fuse + logits mix
  k_fused2<<<dim3(2048), dim3(256), 0, stream>>>(qtb, scoresB, ssP, fsP, ffP,
                                                 temp, attn_w, logits, out, comb);
}

// Round 13
// 146.282 us; speedup vs baseline: 2.6981x; 1.2883x over previous
//
#include <hip/hip_runtime.h>
#include <math.h>

#define B_N 8192
#define D_N 512
#define S_N 5
#define C_N 2048
#define H_N 4

typedef __attribute__((ext_vector_type(8))) short bf16x8;
typedef __attribute__((ext_vector_type(4))) float floatx4;

__device__ __forceinline__ float bf2f(short u) {
  union { unsigned int i; float f; } c;
  c.i = ((unsigned int)(unsigned short)u) << 16;
  return c.f;
}
__device__ __forceinline__ short f2bf(float f) {
  union { float f; unsigned int i; } c; c.f = f;
  unsigned int x = c.i;
  x += 0x7fffu + ((x >> 16) & 1u);   // round-to-nearest-even
  return (short)(x >> 16);
}
__device__ __forceinline__ unsigned long long pack4(float a, float b, float c, float d) {
  return (unsigned long long)(unsigned short)f2bf(a)
       | ((unsigned long long)(unsigned short)f2bf(b) << 16)
       | ((unsigned long long)(unsigned short)f2bf(c) << 32)
       | ((unsigned long long)(unsigned short)f2bf(d) << 48);
}

// ---------------- prep: f->bf16 cvt + WqT transpose + Wk->bf16 (R8 verbatim, passed) ----
__global__ __launch_bounds__(256) void k_prep(
    const float* __restrict__ f, const float* __restrict__ Wq,
    const float* __restrict__ Wk, short* __restrict__ fbf,
    short* __restrict__ WqT, short* __restrict__ Wkb) {
  __shared__ float lds[64][65];
  const int bx = blockIdx.x, t = threadIdx.x;
  if (bx < 2048) {
    int i = bx * 256 + t;
    const floatx4* p = (const floatx4*)(f + (size_t)i * 8);
    floatx4 a = p[0], b = p[1];
    *(unsigned long long*)(fbf + (size_t)i * 8)     = pack4(a[0], a[1], a[2], a[3]);
    *(unsigned long long*)(fbf + (size_t)i * 8 + 4) = pack4(b[0], b[1], b[2], b[3]);
  } else if (bx < 2112) {
    const int bb = bx - 2048;
    const int r0 = (bb >> 3) * 64, c0 = (bb & 7) * 64;
#pragma unroll
    for (int i = 0; i < 16; ++i) {
      int r = i * 4 + (t >> 6), c = t & 63;
      lds[r][c] = Wq[(size_t)(r0 + r) * 512 + c0 + c];
    }
    __syncthreads();
#pragma unroll
    for (int i = 0; i < 16; ++i) {
      int cL = i * 4 + (t >> 6), rL = t & 63;
      WqT[(size_t)(c0 + cL) * 512 + r0 + rL] = f2bf(lds[rL][cL]);
    }
  } else {
    const int base = (bx - 2112) * 8192 + t * 4;
#pragma unroll
    for (int i = 0; i < 8; ++i) {
      int idx = base + i * 1024;
      floatx4 v = *(const floatx4*)(Wk + idx);
      *(unsigned long long*)(Wkb + idx) = pack4(v[0], v[1], v[2], v[3]);
    }
  }
}

__device__ __forceinline__ void gll(const short* g, short* l) {
  __builtin_amdgcn_global_load_lds(
      (const __attribute__((address_space(1))) unsigned int*)(g),
      (__attribute__((address_space(3))) unsigned int*)(l), 16, 0, 0);
}

// ---------------- gemmQR: merged Q-GEMM (K=512) + qt epilogue + R-GEMM from LDS --------
// grid (4 heads, 128 row-tiles). Phase A: Q-tile (64 rows x head's 128 cols) = R9 loop
// verbatim; Q -> LDS Qt (bf16, padded). Phase B: R[rows, h*512+a] = Qt @ Wkb^T, A-frags
// from LDS (no staging, no extra barriers), B direct from L2.
// FIX vs R12: phase-B B-fragment column now includes the wc*64 wave offset (was the bug).
__global__ __launch_bounds__(256) void k_gemmQR(
    const short* __restrict__ A,            // fbf [8192][512]
    const short* __restrict__ BT,           // WqT [512][512]
    const short* __restrict__ Wkb,          // [512][512] (a-major)
    short* __restrict__ Rbf,                // [8192][2048]
    const float* __restrict__ bias,         // bq
    float* __restrict__ qtp, const float* __restrict__ bkp) {
  __shared__ __align__(16) short As[2][2048];
  __shared__ __align__(16) short Bs[2][4096];
  __shared__ __align__(16) short Qt[64][132];   // padded bf16 Q-tile
  __shared__ float qtLds[64][2];

  const int tid = threadIdx.x;
  const int lane = tid & 63;
  const int wid = tid >> 6;
  const int wr = wid >> 1, wc = wid & 1;
  const int h = blockIdx.x;
  const int row0 = blockIdx.y * 64;
  const int col0 = h * 128;

  const int r1 = tid >> 2, hk = tid & 3;
  const short* Ag1 = A + (size_t)(row0 + r1) * 512 + hk * 8;
  const short* Bg1 = BT + (size_t)(col0 + r1) * 512 + hk * 8;
  const short* Bg2 = BT + (size_t)(col0 + 64 + r1) * 512 + hk * 8;

  floatx4 acc[2][4];
  const floatx4 zero = {0.0f, 0.0f, 0.0f, 0.0f};
#pragma unroll
  for (int m = 0; m < 2; ++m)
#pragma unroll
    for (int n = 0; n < 4; ++n) acc[m][n] = zero;

  int cur = 0;
  auto stage = [&](int q, int kb) {
    gll(Ag1 + kb, &As[q][tid * 8]);
    gll(Bg1 + kb, &Bs[q][tid * 8]);
    gll(Bg2 + kb, &Bs[q][tid * 8 + 2048]);
  };

  stage(0, 0);
  __syncthreads();

  for (int t = 0; t < 16; ++t) {          // K=512
    if (t + 1 < 16) stage(cur ^ 1, (t + 1) * 32);
    bf16x8 af[2], bfr[4];
#pragma unroll
    for (int m = 0; m < 2; ++m)
      af[m] = *(const bf16x8*)&As[cur][(wr * 32 + m * 16 + (lane & 15)) * 32 + (lane >> 4) * 8];
#pragma unroll
    for (int n = 0; n < 4; ++n)
      bfr[n] = *(const bf16x8*)&Bs[cur][(wc * 64 + n * 16 + (lane & 15)) * 32 + (lane >> 4) * 8];
#pragma unroll
    for (int m = 0; m < 2; ++m)
#pragma unroll
      for (int n = 0; n < 4; ++n)
        acc[m][n] = __builtin_amdgcn_mfma_f32_16x16x32_bf16(af[m], bfr[n], acc[m][n], 0, 0, 0);
    __syncthreads();
    cur ^= 1;
  }

  // ---- epilogue A: bias, qt partials, Q -> LDS Qt ----
  float qp[2][4] = {{0, 0, 0, 0}, {0, 0, 0, 0}};
#pragma unroll
  for (int m = 0; m < 2; ++m) {
    int lrow0 = wr * 32 + m * 16 + (lane >> 4) * 4;
#pragma unroll
    for (int n = 0; n < 4; ++n) {
      int lc = wc * 64 + n * 16 + (lane & 15);     // local col within head
      float bv = bias[col0 + lc];
      float bkv = bkp[col0 + lc];
#pragma unroll
      for (int j = 0; j < 4; ++j) {
        float q = acc[m][n][j] + bv;
        Qt[lrow0 + j][lc] = f2bf(q);
        qp[m][j] += q * bkv;
      }
    }
  }

#pragma unroll
  for (int m = 0; m < 2; ++m)
#pragma unroll
    for (int j = 0; j < 4; ++j) {
      float p = qp[m][j];
      p += __shfl_xor(p, 1, 64);
      p += __shfl_xor(p, 2, 64);
      p += __shfl_xor(p, 4, 64);
      p += __shfl_xor(p, 8, 64);
      int lrow = wr * 32 + m * 16 + (lane >> 4) * 4 + j;
      if ((lane & 15) == 0) qtLds[lrow][wc] = p;
    }
  __syncthreads();                        // Qt + qtLds visible
  if (tid < 64)
    qtp[(size_t)(row0 + tid) * H_N + h] = qtLds[tid][0] + qtLds[tid][1];

  // ---- phase B: R chunk-by-chunk; A from Qt (LDS), B from Wkb (L2) ----
  for (int cc = 0; cc < 4; ++cc) {
    floatx4 acc2[2][4];
#pragma unroll
    for (int m = 0; m < 2; ++m)
#pragma unroll
      for (int n = 0; n < 4; ++n) acc2[m][n] = zero;

#pragma unroll
    for (int ks = 0; ks < 4; ++ks) {      // K=128 (head-local j)
      bf16x8 af[2], bfr[4];
#pragma unroll
      for (int m = 0; m < 2; ++m)
        af[m] = *(const bf16x8*)&Qt[wr * 32 + m * 16 + (lane & 15)][ks * 32 + (lane >> 4) * 8];
#pragma unroll
      for (int n = 0; n < 4; ++n) {
        int a = cc * 128 + wc * 64 + n * 16 + (lane & 15);   // FIX: + wc*64
        bfr[n] = *(const bf16x8*)(Wkb + (size_t)a * 512 + col0 + ks * 32 + (lane >> 4) * 8);
      }
#pragma unroll
      for (int m = 0; m < 2; ++m)
#pragma unroll
        for (int n = 0; n < 4; ++n)
          acc2[m][n] = __builtin_amdgcn_mfma_f32_16x16x32_bf16(af[m], bfr[n], acc2[m][n], 0, 0, 0);
    }

#pragma unroll
    for (int m = 0; m < 2; ++m) {
      int rowb = row0 + wr * 32 + m * 16 + (lane >> 4) * 4;
#pragma unroll
      for (int n = 0; n < 4; ++n) {
        int ocol = h * 512 + cc * 128 + wc * 64 + n * 16 + (lane & 15);
#pragma unroll
        for (int j = 0; j < 4; ++j)
          Rbf[(size_t)(rowb + j) * 2048 + ocol] = f2bf(acc2[m][n][j]);
      }
    }
  }
}

// ---------------- fused stats + attention + logits mix (R9 verbatim, passed) -----------
__global__ __launch_bounds__(256, 4) void k_fused(
    const float* __restrict__ f, const float* __restrict__ sf,
    const float* __restrict__ emb, const float* __restrict__ qt,
    const short* __restrict__ Rbf, const float* __restrict__ temp,
    const float* __restrict__ attn_w, const float* __restrict__ logits,
    float* __restrict__ out, float* __restrict__ comb_out) {
  const int lane = threadIdx.x & 63;
  const int wid = threadIdx.x >> 6;
  const int b = blockIdx.x * 4 + wid;
  const int a0 = lane * 8;

  const floatx4* fp = (const floatx4*)(f + (size_t)b * D_N + a0);
  floatx4 fA = fp[0], fB = fp[1];
  float fv[8];
#pragma unroll
  for (int j = 0; j < 4; ++j) { fv[j] = fA[j]; fv[4 + j] = fB[j]; }
  float ffp = 0;
#pragma unroll
  for (int j = 0; j < 8; ++j) ffp += fv[j] * fv[j];

  const floatx4 qtv = *(const floatx4*)(qt + (size_t)b * H_N);

  bf16x8 rv[H_N];
#pragma unroll
  for (int h = 0; h < H_N; ++h)
    rv[h] = *(const bf16x8*)(Rbf + (size_t)b * 2048 + h * 512 + a0);

  float fs_[S_N], ss_[S_N], sc_[S_N][H_N];

#pragma unroll
  for (int s = 0; s < S_N; ++s) {
    const floatx4* sp = (const floatx4*)(sf + ((size_t)s * B_N + b) * D_N + a0);
    floatx4 sA = sp[0], sB = sp[1];
    const floatx4* ep = (const floatx4*)(emb + (size_t)s * D_N + a0);
    floatx4 eA = ep[0], eB = ep[1];
    float sv[8], se[8];
#pragma unroll
    for (int j = 0; j < 4; ++j) {
      sv[j] = sA[j]; sv[4 + j] = sB[j];
      se[j] = sA[j] + eA[j]; se[4 + j] = sB[j] + eB[j];
    }
    float fsp = 0, ssp = 0;
    float scp[H_N] = {0, 0, 0, 0};
#pragma unroll
    for (int j = 0; j < 8; ++j) {
      fsp += fv[j] * sv[j];
      ssp += sv[j] * sv[j];
#pragma unroll
      for (int h = 0; h < H_N; ++h) scp[h] += se[j] * bf2f(rv[h][j]);
    }
    fs_[s] = fsp; ss_[s] = ssp;
#pragma unroll
    for (int h = 0; h < H_N; ++h) sc_[s][h] = scp[h];
  }

  float ffv = ffp;
#pragma unroll
  for (int o = 1; o < 64; o <<= 1) {
    ffv += __shfl_xor(ffv, o, 64);
#pragma unroll
    for (int s = 0; s < S_N; ++s) {
      fs_[s] += __shfl_xor(fs_[s], o, 64);
      ss_[s] += __shfl_xor(ss_[s], o, 64);
#pragma unroll
      for (int h = 0; h < H_N; ++h) sc_[s][h] += __shfl_xor(sc_[s][h], o, 64);
    }
  }

  const float t = fabsf(temp[0]);

  float amha[S_N] = {0, 0, 0, 0, 0};
  const float inv_mha = 1.0f / (sqrtf(128.0f) * t);
#pragma unroll
  for (int h = 0; h < H_N; ++h) {
    float lg[S_N];
#pragma unroll
    for (int s = 0; s < S_N; ++s) lg[s] = (sc_[s][h] + qtv[h]) * inv_mha;
    float mx = lg[0];
#pragma unroll
    for (int s = 1; s < S_N; ++s) mx = fmaxf(mx, lg[s]);
    float e[S_N], sum = 0;
#pragma unroll
    for (int s = 0; s < S_N; ++s) { e[s] = __expf(lg[s] - mx); sum += e[s]; }
    float isum = 0.25f / sum;
#pragma unroll
    for (int s = 0; s < S_N; ++s) amha[s] += e[s] * isum;
  }

  float ageo[S_N];
  {
    const float nf = fmaxf(sqrtf(ffv), 1e-12f);
    float g[S_N];
#pragma unroll
    for (int s = 0; s < S_N; ++s) {
      float ns = fmaxf(sqrtf(ss_[s]), 1e-12f);
      float cs0 = fs_[s] / (nf * ns);
      cs0 = fminf(fmaxf(cs0, -1.0f + 1e-7f), 1.0f - 1e-7f);
      g[s] = __expf(-acosf(cs0) / t);
    }
    float mx = g[0];
#pragma unroll
    for (int s = 1; s < S_N; ++s) mx = fmaxf(mx, g[s]);
    float sum = 0;
#pragma unroll
    for (int s = 0; s < S_N; ++s) { ageo[s] = __expf(g[s] - mx); sum += ageo[s]; }
#pragma unroll
    for (int s = 0; s < S_N; ++s) ageo[s] /= sum;
  }

  float acay[S_N];
  {
    const float SQ2 = 1.41421356237309515f;
    const float Aff = 0.72f;
    const float Ass = 0.72f - 0.32f * SQ2;
    const float Afs = -(8.0f + 4.0f * SQ2) / 25.0f;
    float lg[S_N];
#pragma unroll
    for (int s = 0; s < S_N; ++s)
      lg[s] = (Aff * ffv + Ass * ss_[s] + Afs * fs_[s]) / t;
    float mx = lg[0];
#pragma unroll
    for (int s = 1; s < S_N; ++s) mx = fmaxf(mx, lg[s]);
    float sum = 0;
#pragma unroll
    for (int s = 0; s < S_N; ++s) { acay[s] = __expf(lg[s] - mx); sum += acay[s]; }
#pragma unroll
    for (int s = 0; s < S_N; ++s) acay[s] /= sum;
  }

  float w0 = attn_w[0], w1 = attn_w[1], w2 = attn_w[2];
  float wm = fmaxf(w0, fmaxf(w1, w2));
  float e0 = __expf(w0 - wm), e1 = __expf(w1 - wm), e2 = __expf(w2 - wm);
  float wsum = e0 + e1 + e2;
  w0 = e0 / wsum; w1 = e1 / wsum; w2 = e2 / wsum;

  float cb[S_N], csum = 0;
#pragma unroll
  for (int s = 0; s < S_N; ++s) {
    cb[s] = w0 * amha[s] + w1 * ageo[s] + w2 * acay[s];
    csum += cb[s];
  }
  float ic = 1.0f / csum;
  float cbn[S_N];
#pragma unroll
  for (int s = 0; s < S_N; ++s) cbn[s] = cb[s] * ic;
  if (lane == 0) {
#pragma unroll
    for (int s = 0; s < S_N; ++s) comb_out[(size_t)b * S_N + s] = cbn[s];
  }

  const floatx4 fz = {0.f, 0.f, 0.f, 0.f};
#pragma unroll
  for (int cj = 0; cj < 4; ++cj) {
    const int c0 = cj * 512 + lane * 8;
    floatx4 accA = fz, accB = fz;
#pragma unroll
    for (int s = 0; s < S_N; ++s) {
      const float* lp = logits + ((size_t)s * B_N + b) * C_N + c0;
      floatx4 lA = *(const floatx4*)lp;
      floatx4 lB = *(const floatx4*)(lp + 4);
      accA += lA * cbn[s];
      accB += lB * cbn[s];
    }
    float* op = out + (size_t)b * C_N + c0;
    *(floatx4*)op = accA;
    *(floatx4*)(op + 4) = accB;
  }
}

extern "C" void kernel_launch(void* const* d_in, const int* in_sizes, int n_in,
                              void* d_out, int out_size, void* d_ws, size_t ws_size,
                              hipStream_t stream) {
  const float* features = (const float*)d_in[0];
  const float* logits   = (const float*)d_in[1];
  const float* sf       = (const float*)d_in[2];
  const float* Wq       = (const float*)d_in[3];
  const float* bq       = (const float*)d_in[4];
  const float* Wk       = (const float*)d_in[5];
  const float* bk       = (const float*)d_in[6];
  const float* emb      = (const float*)d_in[9];
  const float* temp     = (const float*)d_in[10];
  const float* attn_w   = (const float*)d_in[11];

  float* out  = (float*)d_out;
  float* comb = out + (size_t)B_N * C_N;

  char* w = (char*)d_ws;
  short* fbf = (short*)(w);                    // 8192*512  bf16 =  8.39 MB
  short* Rbf = (short*)(w + 16777216);         // 8192*2048 bf16 = 33.55 MB
  short* WqT = (short*)(w + 50331648);         // 512*512   bf16 =  0.52 MB
  short* Wkb = (short*)(w + 50855936);         // 512*512   bf16 =  0.52 MB
  float* qtb = (float*)(w + 51380224);         // 8192*4    f32

  // 1. f->bf16 + WqT transpose + Wk->bf16
  k_prep<<<dim3(2144), dim3(256), 0, stream>>>(features, Wq, Wk, fbf, WqT, Wkb);
  // 2. merged: Q-GEMM (K=512) + qt epilogue + R-GEMM from LDS Q-tile (no Qbf)
  k_gemmQR<<<dim3(4, 128), dim3(256), 0, stream>>>(fbf, WqT, Wkb, Rbf, bq, qtb, bk);
  // 3. fused stats + attentions + fuse + logits mix
  k_fused<<<dim3(2048), dim3(256), 0, stream>>>(features, sf, emb, qtb, Rbf,
                                                temp, attn_w, logits, out, comb);
}